// Round 13
// baseline (142.707 us; speedup 1.0000x reference)
//
#include <hip/hip_runtime.h>
#include <math.h>

typedef float f4 __attribute__((ext_vector_type(4)));

namespace {
constexpr int NZ = 48, NY = 256, NX = 512;
constexpr int SY = NX;            // y stride (elements)
constexpr int SZ = NX * NY;       // z stride (elements)
constexpr int NTOT = NZ * NY * NX;
constexpr float INV_DX = 1.0f / 100000.0f;
constexpr float INV_DY = 1.0f / 100000.0f;
constexpr float INV_DZ = 1.0f / 500.0f;
}

__device__ __forceinline__ f4 sp(float s) { return (f4){s, s, s, s}; }

__device__ __forceinline__ f4 ldv(const float* __restrict__ f, int e) {
    return *reinterpret_cast<const f4*>(f + e);
}

__device__ __forceinline__ f4 ntldv(const float* __restrict__ f, int e) {
    return __builtin_nontemporal_load(reinterpret_cast<const f4*>(f + e));
}

// ---- x-axis: per-element window [L | C | R]; thread covers i = x0..x0+3 ----
__device__ __forceinline__ void grad2x(f4 L, f4 C, f4 R, int x0, float inv_h,
                                       f4& g, f4& gg) {
    const float h1 = inv_h, h2 = 0.5f * inv_h;
    float win[12] = {L[0], L[1], L[2], L[3], C[0], C[1], C[2], C[3],
                     R[0], R[1], R[2], R[3]};
#pragma unroll
    for (int j = 0; j < 4; ++j) {
        g[j]  = (win[5 + j] - win[3 + j]) * h2;
        gg[j] = ((win[6 + j] - win[4 + j]) * h2 - (win[4 + j] - win[2 + j]) * h2) * h2;
    }
    if (x0 == 0) {
        g[0]  = (C[1] - C[0]) * h1;
        gg[0] = ((C[2] - C[0]) * h2 - g[0]) * h1;
        gg[1] = ((C[3] - C[1]) * h2 - (C[1] - C[0]) * h1) * h2;
    } else if (x0 == NX - 4) {
        gg[2] = ((C[3] - C[2]) * h1 - (C[2] - C[0]) * h2) * h2;
        g[3]  = (C[3] - C[2]) * h1;
        gg[3] = (g[3] - (C[3] - C[1]) * h2) * h1;
    }
}

__device__ __forceinline__ f4 grad1x(f4 L, f4 C, f4 R, int x0, float inv_h) {
    const float h1 = inv_h, h2 = 0.5f * inv_h;
    f4 g;
    g[0] = (C[1] - L[3]) * h2;
    g[1] = (C[2] - C[0]) * h2;
    g[2] = (C[3] - C[1]) * h2;
    g[3] = (R[0] - C[2]) * h2;
    if (x0 == 0)            g[0] = (C[1] - C[0]) * h1;
    else if (x0 == NX - 4)  g[3] = (C[3] - C[2]) * h1;
    return g;
}

// ---- y/z axes: whole-vector stencil, index i uniform across the f4 ----
__device__ __forceinline__ void grad2v(f4 m2, f4 m1, f4 c, f4 p1, f4 p2,
                                       int i, int n, float inv_h, f4& g, f4& gg) {
    const float h1 = inv_h, h2 = 0.5f * inv_h;
    if (i >= 2 && i <= n - 3) {
        g  = (p1 - m1) * sp(h2);
        gg = ((p2 - c) * sp(h2) - (c - m2) * sp(h2)) * sp(h2);
    } else if (i == 0) {
        g  = (p1 - c) * sp(h1);
        gg = ((p2 - c) * sp(h2) - g) * sp(h1);
    } else if (i == 1) {
        g  = (p1 - m1) * sp(h2);
        gg = ((p2 - c) * sp(h2) - (c - m1) * sp(h1)) * sp(h2);
    } else if (i == n - 2) {
        g  = (p1 - m1) * sp(h2);
        gg = ((p1 - c) * sp(h1) - (c - m2) * sp(h2)) * sp(h2);
    } else { // i == n-1
        g  = (c - m1) * sp(h1);
        gg = (g - (c - m2) * sp(h2)) * sp(h1);
    }
}

__device__ __forceinline__ f4 grad1v(f4 m1, f4 c, f4 p1, int i, int n, float inv_h) {
    if (i == 0)     return (p1 - c) * sp(inv_h);
    if (i == n - 1) return (c - m1) * sp(inv_h);
    return (p1 - m1) * sp(0.5f * inv_h);
}

// r11 structure + sched_barrier(0) fences pinning each halo mega-batch as a
// contiguous block of global_load instructions (the compiler's scheduler
// otherwise splits them into ~13-load sub-batches, capping per-wave MLP).
__global__ __launch_bounds__(256, 2)
void pe_fence(const float* __restrict__ u, const float* __restrict__ v,
              const float* __restrict__ w, const float* __restrict__ T,
              const float* __restrict__ q, const float* __restrict__ p,
              const float* __restrict__ rho,
              const float* __restrict__ F_u, const float* __restrict__ F_v,
              const float* __restrict__ F_w, const float* __restrict__ Q,
              const float* __restrict__ S,
              const float* __restrict__ nu_p, const float* __restrict__ kappa_p,
              float* __restrict__ out) {
    // XCD-aware remap (r3 winner)
    const int bid = blockIdx.x;
    const int xcd = bid & 7;
    const int j = bid >> 3;
    const int z = j >> 4;
    const int yp = (xcd << 4) | (j & 15);
    const int y = (yp << 1) | (threadIdx.x >> 7);
    const int x0 = (threadIdx.x & 127) << 2;
    const int e = z * SZ + y * SY + x0;

    const int xm  = e + ((x0 > 0) ? -4 : 0);
    const int xp  = e + ((x0 < NX - 4) ? 4 : 0);
    const int m1y = e + ((y > 0) ? -SY : 0);
    const int m2y = e + ((y > 1) ? -2 * SY : ((y > 0) ? -SY : 0));
    const int p1y = e + ((y < NY - 1) ? SY : 0);
    const int p2y = e + ((y < NY - 2) ? 2 * SY : ((y < NY - 1) ? SY : 0));
    const int m1z = e + ((z > 0) ? -SZ : 0);
    const int m2z = e + ((z > 1) ? -2 * SZ : ((z > 0) ? -SZ : 0));
    const int p1z = e + ((z < NZ - 1) ? SZ : 0);
    const int p2z = e + ((z < NZ - 2) ? 2 * SZ : ((z < NZ - 1) ? SZ : 0));

    // region 0: streamed-once forcings (nt) + centers
    const f4 fFu = ntldv(F_u, e);
    const f4 fFv = ntldv(F_v, e);
    const f4 fFw = ntldv(F_w, e);
    const f4 fQ  = ntldv(Q, e);
    const f4 fS  = ntldv(S, e);
    const f4 uc = ldv(u, e), vc = ldv(v, e), wc = ldv(w, e);
    const f4 pc = ldv(p, e), rhoc = ldv(rho, e);

    __builtin_amdgcn_sched_barrier(0);

    // ===== BATCH A (pinned contiguous): u, v, w, p halos — 36 loads =====
    const f4 u_xm = ldv(u, xm),  u_xp = ldv(u, xp);
    const f4 u_1y = ldv(u, m1y), u_2y = ldv(u, m2y);
    const f4 u_3y = ldv(u, p1y), u_4y = ldv(u, p2y);
    const f4 u_1z = ldv(u, m1z), u_2z = ldv(u, m2z);
    const f4 u_3z = ldv(u, p1z), u_4z = ldv(u, p2z);

    const f4 v_xm = ldv(v, xm),  v_xp = ldv(v, xp);
    const f4 v_1y = ldv(v, m1y), v_2y = ldv(v, m2y);
    const f4 v_3y = ldv(v, p1y), v_4y = ldv(v, p2y);
    const f4 v_1z = ldv(v, m1z), v_2z = ldv(v, m2z);
    const f4 v_3z = ldv(v, p1z), v_4z = ldv(v, p2z);

    const f4 w_xm = ldv(w, xm),  w_xp = ldv(w, xp);
    const f4 w_1y = ldv(w, m1y), w_2y = ldv(w, m2y);
    const f4 w_3y = ldv(w, p1y), w_4y = ldv(w, p2y);
    const f4 w_1z = ldv(w, m1z), w_2z = ldv(w, m2z);
    const f4 w_3z = ldv(w, p1z), w_4z = ldv(w, p2z);

    const f4 p_xm = ldv(p, xm),  p_xp = ldv(p, xp);
    const f4 p_1y = ldv(p, m1y), p_3y = ldv(p, p1y);
    const f4 p_1z = ldv(p, m1z), p_3z = ldv(p, p1z);

    __builtin_amdgcn_sched_barrier(0);

    const float snu = nu_p[0];
    const float lat = -1.57079632679f + (3.14159265359f / 255.0f) * (float)y;
    const float fc = 2.0f * 7.2921e-5f * __sinf(lat);

    f4 gx, gy, gz, ggx, ggy, ggz;

    // u
    grad2x(u_xm, uc, u_xp, x0, INV_DX, gx, ggx);
    grad2v(u_2y, u_1y, uc, u_3y, u_4y, y, NY, INV_DY, gy, ggy);
    grad2v(u_2z, u_1z, uc, u_3z, u_4z, z, NZ, INV_DZ, gz, ggz);
    const f4 du_dx = gx;
    f4 acc_u = sp(snu) * (ggx + ggy + ggz) - (uc * gx + vc * gy + wc * gz);

    // v
    grad2x(v_xm, vc, v_xp, x0, INV_DX, gx, ggx);
    grad2v(v_2y, v_1y, vc, v_3y, v_4y, y, NY, INV_DY, gy, ggy);
    grad2v(v_2z, v_1z, vc, v_3z, v_4z, z, NZ, INV_DZ, gz, ggz);
    const f4 dv_dy = gy;
    f4 acc_v = sp(snu) * (ggx + ggy + ggz) - (uc * gx + vc * gy + wc * gz);

    // w
    grad2x(w_xm, wc, w_xp, x0, INV_DX, gx, ggx);
    grad2v(w_2y, w_1y, wc, w_3y, w_4y, y, NY, INV_DY, gy, ggy);
    grad2v(w_2z, w_1z, wc, w_3z, w_4z, z, NZ, INV_DZ, gz, ggz);
    const f4 dw_dz = gz;
    f4 acc_w = sp(snu) * (ggx + ggy + ggz) - (uc * gx + vc * gy + wc * gz);

    const f4 div = du_dx + dv_dy + dw_dz;

    // p grad1
    const f4 gpx = grad1x(p_xm, pc, p_xp, x0, INV_DX);
    const f4 gpy = grad1v(p_1y, pc, p_3y, y, NY, INV_DY);
    const f4 dpz = grad1v(p_1z, pc, p_3z, z, NZ, INV_DZ);

    const f4 inv_rs = sp(1.0f) / (rhoc + sp(1e-10f));
    acc_u += fFu - gpx * inv_rs + sp(fc) * vc;
    acc_v += fFv - gpy * inv_rs - sp(fc) * uc;
    acc_w += fFw - dpz * inv_rs - sp(9.80665f);

    *reinterpret_cast<f4*>(out + 0 * NTOT + e) = acc_u;
    *reinterpret_cast<f4*>(out + 1 * NTOT + e) = acc_v;
    *reinterpret_cast<f4*>(out + 2 * NTOT + e) = acc_w;

    __builtin_amdgcn_sched_barrier(0);

    // ===== BATCH B (pinned contiguous): T, q, rho halos — 23 loads =====
    const f4 Tc = ldv(T, e);
    const f4 T_xm = ldv(T, xm),  T_xp = ldv(T, xp);
    const f4 T_1y = ldv(T, m1y), T_2y = ldv(T, m2y);
    const f4 T_3y = ldv(T, p1y), T_4y = ldv(T, p2y);
    const f4 T_1z = ldv(T, m1z), T_2z = ldv(T, m2z);
    const f4 T_3z = ldv(T, p1z), T_4z = ldv(T, p2z);

    const f4 qc = ldv(q, e);
    const f4 q_xm = ldv(q, xm),  q_xp = ldv(q, xp);
    const f4 q_1y = ldv(q, m1y), q_3y = ldv(q, p1y);
    const f4 q_1z = ldv(q, m1z), q_3z = ldv(q, p1z);

    const f4 r_xm = ldv(rho, xm),  r_xp = ldv(rho, xp);
    const f4 r_1y = ldv(rho, m1y), r_3y = ldv(rho, p1y);
    const f4 r_1z = ldv(rho, m1z), r_3z = ldv(rho, p1z);

    __builtin_amdgcn_sched_barrier(0);

    const float skap = kappa_p[0];

    // T grad2
    grad2x(T_xm, Tc, T_xp, x0, INV_DX, gx, ggx);
    grad2v(T_2y, T_1y, Tc, T_3y, T_4y, y, NY, INV_DY, gy, ggy);
    grad2v(T_2z, T_1z, Tc, T_3z, T_4z, z, NZ, INV_DZ, gz, ggz);
    f4 acc_T = sp(skap) * (ggx + ggy + ggz) - (uc * gx + vc * gy + wc * gz);
    acc_T += sp(287.0f / 1004.0f) * Tc * wc * dpz / (pc + sp(1e-10f));
    acc_T += fQ * sp(1.0f / 1004.0f);

    // q grad1
    gx = grad1x(q_xm, qc, q_xp, x0, INV_DX);
    gy = grad1v(q_1y, qc, q_3y, y, NY, INV_DY);
    gz = grad1v(q_1z, qc, q_3z, z, NZ, INV_DZ);
    const f4 acc_q = fS - (uc * gx + vc * gy + wc * gz);

    // rho grad1
    gx = grad1x(r_xm, rhoc, r_xp, x0, INV_DX);
    gy = grad1v(r_1y, rhoc, r_3y, y, NY, INV_DY);
    gz = grad1v(r_1z, rhoc, r_3z, z, NZ, INV_DZ);
    const f4 acc_rho = -rhoc * div - uc * gx - vc * gy - wc * gz;

    const f4 acc_p = sp(287.0f) * (rhoc * acc_T + Tc * acc_rho);

    *reinterpret_cast<f4*>(out + 3 * NTOT + e) = acc_T;
    *reinterpret_cast<f4*>(out + 4 * NTOT + e) = acc_q;
    *reinterpret_cast<f4*>(out + 5 * NTOT + e) = acc_p;
    *reinterpret_cast<f4*>(out + 6 * NTOT + e) = acc_rho;
}

extern "C" void kernel_launch(void* const* d_in, const int* in_sizes, int n_in,
                              void* d_out, int out_size, void* d_ws, size_t ws_size,
                              hipStream_t stream) {
    const float* u     = (const float*)d_in[0];
    const float* v     = (const float*)d_in[1];
    const float* w     = (const float*)d_in[2];
    const float* T     = (const float*)d_in[3];
    const float* q     = (const float*)d_in[4];
    const float* p     = (const float*)d_in[5];
    const float* rho   = (const float*)d_in[6];
    const float* F_u   = (const float*)d_in[7];
    const float* F_v   = (const float*)d_in[8];
    const float* F_w   = (const float*)d_in[9];
    const float* Q     = (const float*)d_in[10];
    const float* S     = (const float*)d_in[11];
    const float* nu    = (const float*)d_in[12];
    const float* kappa = (const float*)d_in[13];
    float* out = (float*)d_out;

    pe_fence<<<6144, 256, 0, stream>>>(u, v, w, T, q, p, rho,
                                       F_u, F_v, F_w, Q, S, nu, kappa, out);
}

// Round 14
// 130.218 us; speedup vs baseline: 1.0959x; 1.0959x over previous
//
#include <hip/hip_runtime.h>
#include <math.h>

typedef float f4 __attribute__((ext_vector_type(4)));

namespace {
constexpr int NZ = 48, NY = 256, NX = 512;
constexpr int SY = NX;            // y stride (elements)
constexpr int SZ = NX * NY;       // z stride (elements)
constexpr int NTOT = NZ * NY * NX;
constexpr float INV_DX = 1.0f / 100000.0f;
constexpr float INV_DY = 1.0f / 100000.0f;
constexpr float INV_DZ = 1.0f / 500.0f;
}

__device__ __forceinline__ f4 sp(float s) { return (f4){s, s, s, s}; }

__device__ __forceinline__ f4 ldv(const float* __restrict__ f, int e) {
    return *reinterpret_cast<const f4*>(f + e);
}

__device__ __forceinline__ f4 ntldv(const float* __restrict__ f, int e) {
    return __builtin_nontemporal_load(reinterpret_cast<const f4*>(f + e));
}

// ---- x-axis: per-element window [L | C | R]; thread covers i = x0..x0+3 ----
__device__ __forceinline__ void grad2x(f4 L, f4 C, f4 R, int x0, float inv_h,
                                       f4& g, f4& gg) {
    const float h1 = inv_h, h2 = 0.5f * inv_h;
    float win[12] = {L[0], L[1], L[2], L[3], C[0], C[1], C[2], C[3],
                     R[0], R[1], R[2], R[3]};
#pragma unroll
    for (int j = 0; j < 4; ++j) {
        g[j]  = (win[5 + j] - win[3 + j]) * h2;
        gg[j] = ((win[6 + j] - win[4 + j]) * h2 - (win[4 + j] - win[2 + j]) * h2) * h2;
    }
    if (x0 == 0) {
        g[0]  = (C[1] - C[0]) * h1;
        gg[0] = ((C[2] - C[0]) * h2 - g[0]) * h1;
        gg[1] = ((C[3] - C[1]) * h2 - (C[1] - C[0]) * h1) * h2;
    } else if (x0 == NX - 4) {
        gg[2] = ((C[3] - C[2]) * h1 - (C[2] - C[0]) * h2) * h2;
        g[3]  = (C[3] - C[2]) * h1;
        gg[3] = (g[3] - (C[3] - C[1]) * h2) * h1;
    }
}

__device__ __forceinline__ f4 grad1x(f4 L, f4 C, f4 R, int x0, float inv_h) {
    const float h1 = inv_h, h2 = 0.5f * inv_h;
    f4 g;
    g[0] = (C[1] - L[3]) * h2;
    g[1] = (C[2] - C[0]) * h2;
    g[2] = (C[3] - C[1]) * h2;
    g[3] = (R[0] - C[2]) * h2;
    if (x0 == 0)            g[0] = (C[1] - C[0]) * h1;
    else if (x0 == NX - 4)  g[3] = (C[3] - C[2]) * h1;
    return g;
}

// ---- y/z axes: whole-vector stencil, index i uniform across the f4 ----
__device__ __forceinline__ void grad2v(f4 m2, f4 m1, f4 c, f4 p1, f4 p2,
                                       int i, int n, float inv_h, f4& g, f4& gg) {
    const float h1 = inv_h, h2 = 0.5f * inv_h;
    if (i >= 2 && i <= n - 3) {
        g  = (p1 - m1) * sp(h2);
        gg = ((p2 - c) * sp(h2) - (c - m2) * sp(h2)) * sp(h2);
    } else if (i == 0) {
        g  = (p1 - c) * sp(h1);
        gg = ((p2 - c) * sp(h2) - g) * sp(h1);
    } else if (i == 1) {
        g  = (p1 - m1) * sp(h2);
        gg = ((p2 - c) * sp(h2) - (c - m1) * sp(h1)) * sp(h2);
    } else if (i == n - 2) {
        g  = (p1 - m1) * sp(h2);
        gg = ((p1 - c) * sp(h1) - (c - m2) * sp(h2)) * sp(h2);
    } else { // i == n-1
        g  = (c - m1) * sp(h1);
        gg = (g - (c - m2) * sp(h2)) * sp(h1);
    }
}

__device__ __forceinline__ f4 grad1v(f4 m1, f4 c, f4 p1, int i, int n, float inv_h) {
    if (i == 0)     return (p1 - c) * sp(inv_h);
    if (i == n - 1) return (c - m1) * sp(inv_h);
    return (p1 - m1) * sp(0.5f * inv_h);
}

// r11 structure with LATENCY-ORDERED issue: z-forward planes (z+1, z+2 — the
// only loads this XCD's band sweep hasn't warmed into L2 => L3/HBM latency)
// and the NT forcing streams issue FIRST, overlapping the entire batch-A
// issue + momentum compute. Everything else identical to r11.
__global__ __launch_bounds__(256, 2)
void pe_zfwd(const float* __restrict__ u, const float* __restrict__ v,
             const float* __restrict__ w, const float* __restrict__ T,
             const float* __restrict__ q, const float* __restrict__ p,
             const float* __restrict__ rho,
             const float* __restrict__ F_u, const float* __restrict__ F_v,
             const float* __restrict__ F_w, const float* __restrict__ Q,
             const float* __restrict__ S,
             const float* __restrict__ nu_p, const float* __restrict__ kappa_p,
             float* __restrict__ out) {
    // XCD-aware remap (r3 winner)
    const int bid = blockIdx.x;
    const int xcd = bid & 7;
    const int j = bid >> 3;
    const int z = j >> 4;
    const int yp = (xcd << 4) | (j & 15);
    const int y = (yp << 1) | (threadIdx.x >> 7);
    const int x0 = (threadIdx.x & 127) << 2;
    const int e = z * SZ + y * SY + x0;

    const int xm  = e + ((x0 > 0) ? -4 : 0);
    const int xp  = e + ((x0 < NX - 4) ? 4 : 0);
    const int m1y = e + ((y > 0) ? -SY : 0);
    const int m2y = e + ((y > 1) ? -2 * SY : ((y > 0) ? -SY : 0));
    const int p1y = e + ((y < NY - 1) ? SY : 0);
    const int p2y = e + ((y < NY - 2) ? 2 * SY : ((y < NY - 1) ? SY : 0));
    const int m1z = e + ((z > 0) ? -SZ : 0);
    const int m2z = e + ((z > 1) ? -2 * SZ : ((z > 0) ? -SZ : 0));
    const int p1z = e + ((z < NZ - 1) ? SZ : 0);
    const int p2z = e + ((z < NZ - 2) ? 2 * SZ : ((z < NZ - 1) ? SZ : 0));

    // ===== region 0: LONGEST-LATENCY loads first =====
    // z-forward planes for the momentum fields (cold in this XCD's L2)
    const f4 u_3z = ldv(u, p1z), u_4z = ldv(u, p2z);
    const f4 v_3z = ldv(v, p1z), v_4z = ldv(v, p2z);
    const f4 w_3z = ldv(w, p1z), w_4z = ldv(w, p2z);
    const f4 p_3z = ldv(p, p1z);
    // streamed-once forcings (HBM streams, non-temporal)
    const f4 fFu = ntldv(F_u, e);
    const f4 fFv = ntldv(F_v, e);
    const f4 fFw = ntldv(F_w, e);
    const f4 fQ  = ntldv(Q, e);
    const f4 fS  = ntldv(S, e);
    // centers
    const f4 uc = ldv(u, e), vc = ldv(v, e), wc = ldv(w, e);
    const f4 pc = ldv(p, e), rhoc = ldv(rho, e);

    __builtin_amdgcn_sched_barrier(0);

    // ===== BATCH A: remaining u, v, w, p halos (L2-warm) =====
    const f4 u_xm = ldv(u, xm),  u_xp = ldv(u, xp);
    const f4 u_1y = ldv(u, m1y), u_2y = ldv(u, m2y);
    const f4 u_3y = ldv(u, p1y), u_4y = ldv(u, p2y);
    const f4 u_1z = ldv(u, m1z), u_2z = ldv(u, m2z);

    const f4 v_xm = ldv(v, xm),  v_xp = ldv(v, xp);
    const f4 v_1y = ldv(v, m1y), v_2y = ldv(v, m2y);
    const f4 v_3y = ldv(v, p1y), v_4y = ldv(v, p2y);
    const f4 v_1z = ldv(v, m1z), v_2z = ldv(v, m2z);

    const f4 w_xm = ldv(w, xm),  w_xp = ldv(w, xp);
    const f4 w_1y = ldv(w, m1y), w_2y = ldv(w, m2y);
    const f4 w_3y = ldv(w, p1y), w_4y = ldv(w, p2y);
    const f4 w_1z = ldv(w, m1z), w_2z = ldv(w, m2z);

    const f4 p_xm = ldv(p, xm),  p_xp = ldv(p, xp);
    const f4 p_1y = ldv(p, m1y), p_3y = ldv(p, p1y);
    const f4 p_1z = ldv(p, m1z);

    const float snu = nu_p[0];
    const float lat = -1.57079632679f + (3.14159265359f / 255.0f) * (float)y;
    const float fc = 2.0f * 7.2921e-5f * __sinf(lat);

    f4 gx, gy, gz, ggx, ggy, ggz;

    // u
    grad2x(u_xm, uc, u_xp, x0, INV_DX, gx, ggx);
    grad2v(u_2y, u_1y, uc, u_3y, u_4y, y, NY, INV_DY, gy, ggy);
    grad2v(u_2z, u_1z, uc, u_3z, u_4z, z, NZ, INV_DZ, gz, ggz);
    const f4 du_dx = gx;
    f4 acc_u = sp(snu) * (ggx + ggy + ggz) - (uc * gx + vc * gy + wc * gz);

    // v
    grad2x(v_xm, vc, v_xp, x0, INV_DX, gx, ggx);
    grad2v(v_2y, v_1y, vc, v_3y, v_4y, y, NY, INV_DY, gy, ggy);
    grad2v(v_2z, v_1z, vc, v_3z, v_4z, z, NZ, INV_DZ, gz, ggz);
    const f4 dv_dy = gy;
    f4 acc_v = sp(snu) * (ggx + ggy + ggz) - (uc * gx + vc * gy + wc * gz);

    // w
    grad2x(w_xm, wc, w_xp, x0, INV_DX, gx, ggx);
    grad2v(w_2y, w_1y, wc, w_3y, w_4y, y, NY, INV_DY, gy, ggy);
    grad2v(w_2z, w_1z, wc, w_3z, w_4z, z, NZ, INV_DZ, gz, ggz);
    const f4 dw_dz = gz;
    f4 acc_w = sp(snu) * (ggx + ggy + ggz) - (uc * gx + vc * gy + wc * gz);

    const f4 div = du_dx + dv_dy + dw_dz;

    // p grad1
    const f4 gpx = grad1x(p_xm, pc, p_xp, x0, INV_DX);
    const f4 gpy = grad1v(p_1y, pc, p_3y, y, NY, INV_DY);
    const f4 dpz = grad1v(p_1z, pc, p_3z, z, NZ, INV_DZ);

    const f4 inv_rs = sp(1.0f) / (rhoc + sp(1e-10f));
    acc_u += fFu - gpx * inv_rs + sp(fc) * vc;
    acc_v += fFv - gpy * inv_rs - sp(fc) * uc;
    acc_w += fFw - dpz * inv_rs - sp(9.80665f);

    *reinterpret_cast<f4*>(out + 0 * NTOT + e) = acc_u;
    *reinterpret_cast<f4*>(out + 1 * NTOT + e) = acc_v;
    *reinterpret_cast<f4*>(out + 2 * NTOT + e) = acc_w;

    // ===== BATCH B: z-forward first (cold), then L2-warm halos =====
    const f4 T_3z = ldv(T, p1z), T_4z = ldv(T, p2z);
    const f4 q_3z = ldv(q, p1z);
    const f4 r_3z = ldv(rho, p1z);

    const f4 Tc = ldv(T, e);
    const f4 T_xm = ldv(T, xm),  T_xp = ldv(T, xp);
    const f4 T_1y = ldv(T, m1y), T_2y = ldv(T, m2y);
    const f4 T_3y = ldv(T, p1y), T_4y = ldv(T, p2y);
    const f4 T_1z = ldv(T, m1z), T_2z = ldv(T, m2z);

    const f4 qc = ldv(q, e);
    const f4 q_xm = ldv(q, xm),  q_xp = ldv(q, xp);
    const f4 q_1y = ldv(q, m1y), q_3y = ldv(q, p1y);
    const f4 q_1z = ldv(q, m1z);

    const f4 r_xm = ldv(rho, xm),  r_xp = ldv(rho, xp);
    const f4 r_1y = ldv(rho, m1y), r_3y = ldv(rho, p1y);
    const f4 r_1z = ldv(rho, m1z);

    const float skap = kappa_p[0];

    // T grad2
    grad2x(T_xm, Tc, T_xp, x0, INV_DX, gx, ggx);
    grad2v(T_2y, T_1y, Tc, T_3y, T_4y, y, NY, INV_DY, gy, ggy);
    grad2v(T_2z, T_1z, Tc, T_3z, T_4z, z, NZ, INV_DZ, gz, ggz);
    f4 acc_T = sp(skap) * (ggx + ggy + ggz) - (uc * gx + vc * gy + wc * gz);
    acc_T += sp(287.0f / 1004.0f) * Tc * wc * dpz / (pc + sp(1e-10f));
    acc_T += fQ * sp(1.0f / 1004.0f);

    // q grad1
    gx = grad1x(q_xm, qc, q_xp, x0, INV_DX);
    gy = grad1v(q_1y, qc, q_3y, y, NY, INV_DY);
    gz = grad1v(q_1z, qc, q_3z, z, NZ, INV_DZ);
    const f4 acc_q = fS - (uc * gx + vc * gy + wc * gz);

    // rho grad1
    gx = grad1x(r_xm, rhoc, r_xp, x0, INV_DX);
    gy = grad1v(r_1y, rhoc, r_3y, y, NY, INV_DY);
    gz = grad1v(r_1z, rhoc, r_3z, z, NZ, INV_DZ);
    const f4 acc_rho = -rhoc * div - uc * gx - vc * gy - wc * gz;

    const f4 acc_p = sp(287.0f) * (rhoc * acc_T + Tc * acc_rho);

    *reinterpret_cast<f4*>(out + 3 * NTOT + e) = acc_T;
    *reinterpret_cast<f4*>(out + 4 * NTOT + e) = acc_q;
    *reinterpret_cast<f4*>(out + 5 * NTOT + e) = acc_p;
    *reinterpret_cast<f4*>(out + 6 * NTOT + e) = acc_rho;
}

extern "C" void kernel_launch(void* const* d_in, const int* in_sizes, int n_in,
                              void* d_out, int out_size, void* d_ws, size_t ws_size,
                              hipStream_t stream) {
    const float* u     = (const float*)d_in[0];
    const float* v     = (const float*)d_in[1];
    const float* w     = (const float*)d_in[2];
    const float* T     = (const float*)d_in[3];
    const float* q     = (const float*)d_in[4];
    const float* p     = (const float*)d_in[5];
    const float* rho   = (const float*)d_in[6];
    const float* F_u   = (const float*)d_in[7];
    const float* F_v   = (const float*)d_in[8];
    const float* F_w   = (const float*)d_in[9];
    const float* Q     = (const float*)d_in[10];
    const float* S     = (const float*)d_in[11];
    const float* nu    = (const float*)d_in[12];
    const float* kappa = (const float*)d_in[13];
    float* out = (float*)d_out;

    pe_zfwd<<<6144, 256, 0, stream>>>(u, v, w, T, q, p, rho,
                                      F_u, F_v, F_w, Q, S, nu, kappa, out);
}

// Round 15
// 125.014 us; speedup vs baseline: 1.1415x; 1.0416x over previous
//
#include <hip/hip_runtime.h>
#include <math.h>

typedef float f4 __attribute__((ext_vector_type(4)));

namespace {
constexpr int NZ = 48, NY = 256, NX = 512;
constexpr int SY = NX;            // y stride (elements)
constexpr int SZ = NX * NY;       // z stride (elements)
constexpr int NTOT = NZ * NY * NX;
constexpr float INV_DX = 1.0f / 100000.0f;
constexpr float INV_DY = 1.0f / 100000.0f;
constexpr float INV_DZ = 1.0f / 500.0f;
}

__device__ __forceinline__ f4 sp(float s) { return (f4){s, s, s, s}; }

__device__ __forceinline__ f4 ldv(const float* __restrict__ f, int e) {
    return *reinterpret_cast<const f4*>(f + e);
}

__device__ __forceinline__ f4 ntldv(const float* __restrict__ f, int e) {
    return __builtin_nontemporal_load(reinterpret_cast<const f4*>(f + e));
}

// ---- x-axis: per-element window [L | C | R]; thread covers i = x0..x0+3 ----
__device__ __forceinline__ void grad2x(f4 L, f4 C, f4 R, int x0, float inv_h,
                                       f4& g, f4& gg) {
    const float h1 = inv_h, h2 = 0.5f * inv_h;
    float win[12] = {L[0], L[1], L[2], L[3], C[0], C[1], C[2], C[3],
                     R[0], R[1], R[2], R[3]};
#pragma unroll
    for (int j = 0; j < 4; ++j) {
        g[j]  = (win[5 + j] - win[3 + j]) * h2;
        gg[j] = ((win[6 + j] - win[4 + j]) * h2 - (win[4 + j] - win[2 + j]) * h2) * h2;
    }
    if (x0 == 0) {
        g[0]  = (C[1] - C[0]) * h1;
        gg[0] = ((C[2] - C[0]) * h2 - g[0]) * h1;
        gg[1] = ((C[3] - C[1]) * h2 - (C[1] - C[0]) * h1) * h2;
    } else if (x0 == NX - 4) {
        gg[2] = ((C[3] - C[2]) * h1 - (C[2] - C[0]) * h2) * h2;
        g[3]  = (C[3] - C[2]) * h1;
        gg[3] = (g[3] - (C[3] - C[1]) * h2) * h1;
    }
}

__device__ __forceinline__ f4 grad1x(f4 L, f4 C, f4 R, int x0, float inv_h) {
    const float h1 = inv_h, h2 = 0.5f * inv_h;
    f4 g;
    g[0] = (C[1] - L[3]) * h2;
    g[1] = (C[2] - C[0]) * h2;
    g[2] = (C[3] - C[1]) * h2;
    g[3] = (R[0] - C[2]) * h2;
    if (x0 == 0)            g[0] = (C[1] - C[0]) * h1;
    else if (x0 == NX - 4)  g[3] = (C[3] - C[2]) * h1;
    return g;
}

// ---- y/z axes: whole-vector stencil, index i uniform across the f4 ----
__device__ __forceinline__ void grad2v(f4 m2, f4 m1, f4 c, f4 p1, f4 p2,
                                       int i, int n, float inv_h, f4& g, f4& gg) {
    const float h1 = inv_h, h2 = 0.5f * inv_h;
    if (i >= 2 && i <= n - 3) {
        g  = (p1 - m1) * sp(h2);
        gg = ((p2 - c) * sp(h2) - (c - m2) * sp(h2)) * sp(h2);
    } else if (i == 0) {
        g  = (p1 - c) * sp(h1);
        gg = ((p2 - c) * sp(h2) - g) * sp(h1);
    } else if (i == 1) {
        g  = (p1 - m1) * sp(h2);
        gg = ((p2 - c) * sp(h2) - (c - m1) * sp(h1)) * sp(h2);
    } else if (i == n - 2) {
        g  = (p1 - m1) * sp(h2);
        gg = ((p1 - c) * sp(h1) - (c - m2) * sp(h2)) * sp(h2);
    } else { // i == n-1
        g  = (c - m1) * sp(h1);
        gg = (g - (c - m2) * sp(h2)) * sp(h1);
    }
}

__device__ __forceinline__ f4 grad1v(f4 m1, f4 c, f4 p1, int i, int n, float inv_h) {
    if (i == 0)     return (p1 - c) * sp(inv_h);
    if (i == n - 1) return (c - m1) * sp(inv_h);
    return (p1 - m1) * sp(0.5f * inv_h);
}

// r14 + FULL cold-set hoist: ALL cold loads (z-forward planes of all 7 fields
// + the 5 NT forcing streams) issue in region 0, overlapping batch-A issue +
// momentum compute. Warm (L2-resident) halos stay near their use.
__global__ __launch_bounds__(256, 2)
void pe_zfwd2(const float* __restrict__ u, const float* __restrict__ v,
              const float* __restrict__ w, const float* __restrict__ T,
              const float* __restrict__ q, const float* __restrict__ p,
              const float* __restrict__ rho,
              const float* __restrict__ F_u, const float* __restrict__ F_v,
              const float* __restrict__ F_w, const float* __restrict__ Q,
              const float* __restrict__ S,
              const float* __restrict__ nu_p, const float* __restrict__ kappa_p,
              float* __restrict__ out) {
    // XCD-aware remap (r3 winner)
    const int bid = blockIdx.x;
    const int xcd = bid & 7;
    const int j = bid >> 3;
    const int z = j >> 4;
    const int yp = (xcd << 4) | (j & 15);
    const int y = (yp << 1) | (threadIdx.x >> 7);
    const int x0 = (threadIdx.x & 127) << 2;
    const int e = z * SZ + y * SY + x0;

    const int xm  = e + ((x0 > 0) ? -4 : 0);
    const int xp  = e + ((x0 < NX - 4) ? 4 : 0);
    const int m1y = e + ((y > 0) ? -SY : 0);
    const int m2y = e + ((y > 1) ? -2 * SY : ((y > 0) ? -SY : 0));
    const int p1y = e + ((y < NY - 1) ? SY : 0);
    const int p2y = e + ((y < NY - 2) ? 2 * SY : ((y < NY - 1) ? SY : 0));
    const int m1z = e + ((z > 0) ? -SZ : 0);
    const int m2z = e + ((z > 1) ? -2 * SZ : ((z > 0) ? -SZ : 0));
    const int p1z = e + ((z < NZ - 1) ? SZ : 0);
    const int p2z = e + ((z < NZ - 2) ? 2 * SZ : ((z < NZ - 1) ? SZ : 0));

    // ===== region 0: ALL long-latency loads =====
    // momentum cold set (z-forward planes)
    const f4 u_3z = ldv(u, p1z), u_4z = ldv(u, p2z);
    const f4 v_3z = ldv(v, p1z), v_4z = ldv(v, p2z);
    const f4 w_3z = ldv(w, p1z), w_4z = ldv(w, p2z);
    const f4 p_3z = ldv(p, p1z);
    // thermo cold set (carried across phase A; +16 VGPR)
    const f4 T_3z = ldv(T, p1z), T_4z = ldv(T, p2z);
    const f4 q_3z = ldv(q, p1z);
    const f4 r_3z = ldv(rho, p1z);
    // streamed-once forcings (HBM streams, non-temporal)
    const f4 fFu = ntldv(F_u, e);
    const f4 fFv = ntldv(F_v, e);
    const f4 fFw = ntldv(F_w, e);
    const f4 fQ  = ntldv(Q, e);
    const f4 fS  = ntldv(S, e);
    // centers
    const f4 uc = ldv(u, e), vc = ldv(v, e), wc = ldv(w, e);
    const f4 pc = ldv(p, e), rhoc = ldv(rho, e);

    __builtin_amdgcn_sched_barrier(0);

    // ===== BATCH A: remaining u, v, w, p halos (L2-warm) =====
    const f4 u_xm = ldv(u, xm),  u_xp = ldv(u, xp);
    const f4 u_1y = ldv(u, m1y), u_2y = ldv(u, m2y);
    const f4 u_3y = ldv(u, p1y), u_4y = ldv(u, p2y);
    const f4 u_1z = ldv(u, m1z), u_2z = ldv(u, m2z);

    const f4 v_xm = ldv(v, xm),  v_xp = ldv(v, xp);
    const f4 v_1y = ldv(v, m1y), v_2y = ldv(v, m2y);
    const f4 v_3y = ldv(v, p1y), v_4y = ldv(v, p2y);
    const f4 v_1z = ldv(v, m1z), v_2z = ldv(v, m2z);

    const f4 w_xm = ldv(w, xm),  w_xp = ldv(w, xp);
    const f4 w_1y = ldv(w, m1y), w_2y = ldv(w, m2y);
    const f4 w_3y = ldv(w, p1y), w_4y = ldv(w, p2y);
    const f4 w_1z = ldv(w, m1z), w_2z = ldv(w, m2z);

    const f4 p_xm = ldv(p, xm),  p_xp = ldv(p, xp);
    const f4 p_1y = ldv(p, m1y), p_3y = ldv(p, p1y);
    const f4 p_1z = ldv(p, m1z);

    const float snu = nu_p[0];
    const float lat = -1.57079632679f + (3.14159265359f / 255.0f) * (float)y;
    const float fc = 2.0f * 7.2921e-5f * __sinf(lat);

    f4 gx, gy, gz, ggx, ggy, ggz;

    // u
    grad2x(u_xm, uc, u_xp, x0, INV_DX, gx, ggx);
    grad2v(u_2y, u_1y, uc, u_3y, u_4y, y, NY, INV_DY, gy, ggy);
    grad2v(u_2z, u_1z, uc, u_3z, u_4z, z, NZ, INV_DZ, gz, ggz);
    const f4 du_dx = gx;
    f4 acc_u = sp(snu) * (ggx + ggy + ggz) - (uc * gx + vc * gy + wc * gz);

    // v
    grad2x(v_xm, vc, v_xp, x0, INV_DX, gx, ggx);
    grad2v(v_2y, v_1y, vc, v_3y, v_4y, y, NY, INV_DY, gy, ggy);
    grad2v(v_2z, v_1z, vc, v_3z, v_4z, z, NZ, INV_DZ, gz, ggz);
    const f4 dv_dy = gy;
    f4 acc_v = sp(snu) * (ggx + ggy + ggz) - (uc * gx + vc * gy + wc * gz);

    // w
    grad2x(w_xm, wc, w_xp, x0, INV_DX, gx, ggx);
    grad2v(w_2y, w_1y, wc, w_3y, w_4y, y, NY, INV_DY, gy, ggy);
    grad2v(w_2z, w_1z, wc, w_3z, w_4z, z, NZ, INV_DZ, gz, ggz);
    const f4 dw_dz = gz;
    f4 acc_w = sp(snu) * (ggx + ggy + ggz) - (uc * gx + vc * gy + wc * gz);

    const f4 div = du_dx + dv_dy + dw_dz;

    // p grad1
    const f4 gpx = grad1x(p_xm, pc, p_xp, x0, INV_DX);
    const f4 gpy = grad1v(p_1y, pc, p_3y, y, NY, INV_DY);
    const f4 dpz = grad1v(p_1z, pc, p_3z, z, NZ, INV_DZ);

    const f4 inv_rs = sp(1.0f) / (rhoc + sp(1e-10f));
    acc_u += fFu - gpx * inv_rs + sp(fc) * vc;
    acc_v += fFv - gpy * inv_rs - sp(fc) * uc;
    acc_w += fFw - dpz * inv_rs - sp(9.80665f);

    *reinterpret_cast<f4*>(out + 0 * NTOT + e) = acc_u;
    *reinterpret_cast<f4*>(out + 1 * NTOT + e) = acc_v;
    *reinterpret_cast<f4*>(out + 2 * NTOT + e) = acc_w;

    // ===== BATCH B: warm thermo halos only (cold set already in flight) ====
    const f4 Tc = ldv(T, e);
    const f4 T_xm = ldv(T, xm),  T_xp = ldv(T, xp);
    const f4 T_1y = ldv(T, m1y), T_2y = ldv(T, m2y);
    const f4 T_3y = ldv(T, p1y), T_4y = ldv(T, p2y);
    const f4 T_1z = ldv(T, m1z), T_2z = ldv(T, m2z);

    const f4 qc = ldv(q, e);
    const f4 q_xm = ldv(q, xm),  q_xp = ldv(q, xp);
    const f4 q_1y = ldv(q, m1y), q_3y = ldv(q, p1y);
    const f4 q_1z = ldv(q, m1z);

    const f4 r_xm = ldv(rho, xm),  r_xp = ldv(rho, xp);
    const f4 r_1y = ldv(rho, m1y), r_3y = ldv(rho, p1y);
    const f4 r_1z = ldv(rho, m1z);

    const float skap = kappa_p[0];

    // T grad2
    grad2x(T_xm, Tc, T_xp, x0, INV_DX, gx, ggx);
    grad2v(T_2y, T_1y, Tc, T_3y, T_4y, y, NY, INV_DY, gy, ggy);
    grad2v(T_2z, T_1z, Tc, T_3z, T_4z, z, NZ, INV_DZ, gz, ggz);
    f4 acc_T = sp(skap) * (ggx + ggy + ggz) - (uc * gx + vc * gy + wc * gz);
    acc_T += sp(287.0f / 1004.0f) * Tc * wc * dpz / (pc + sp(1e-10f));
    acc_T += fQ * sp(1.0f / 1004.0f);

    // q grad1
    gx = grad1x(q_xm, qc, q_xp, x0, INV_DX);
    gy = grad1v(q_1y, qc, q_3y, y, NY, INV_DY);
    gz = grad1v(q_1z, qc, q_3z, z, NZ, INV_DZ);
    const f4 acc_q = fS - (uc * gx + vc * gy + wc * gz);

    // rho grad1
    gx = grad1x(r_xm, rhoc, r_xp, x0, INV_DX);
    gy = grad1v(r_1y, rhoc, r_3y, y, NY, INV_DY);
    gz = grad1v(r_1z, rhoc, r_3z, z, NZ, INV_DZ);
    const f4 acc_rho = -rhoc * div - uc * gx - vc * gy - wc * gz;

    const f4 acc_p = sp(287.0f) * (rhoc * acc_T + Tc * acc_rho);

    *reinterpret_cast<f4*>(out + 3 * NTOT + e) = acc_T;
    *reinterpret_cast<f4*>(out + 4 * NTOT + e) = acc_q;
    *reinterpret_cast<f4*>(out + 5 * NTOT + e) = acc_p;
    *reinterpret_cast<f4*>(out + 6 * NTOT + e) = acc_rho;
}

extern "C" void kernel_launch(void* const* d_in, const int* in_sizes, int n_in,
                              void* d_out, int out_size, void* d_ws, size_t ws_size,
                              hipStream_t stream) {
    const float* u     = (const float*)d_in[0];
    const float* v     = (const float*)d_in[1];
    const float* w     = (const float*)d_in[2];
    const float* T     = (const float*)d_in[3];
    const float* q     = (const float*)d_in[4];
    const float* p     = (const float*)d_in[5];
    const float* rho   = (const float*)d_in[6];
    const float* F_u   = (const float*)d_in[7];
    const float* F_v   = (const float*)d_in[8];
    const float* F_w   = (const float*)d_in[9];
    const float* Q     = (const float*)d_in[10];
    const float* S     = (const float*)d_in[11];
    const float* nu    = (const float*)d_in[12];
    const float* kappa = (const float*)d_in[13];
    float* out = (float*)d_out;

    pe_zfwd2<<<6144, 256, 0, stream>>>(u, v, w, T, q, p, rho,
                                       F_u, F_v, F_w, Q, S, nu, kappa, out);
}